// Round 1
// baseline (415.576 us; speedup 1.0000x reference)
//
#include <hip/hip_runtime.h>

#define SCALE_F 10000.0f
#define PSF 21
#define PAD 10
#define PSF3 9261        // 21*21*21
#define VPT 37           // ceil(9261/256)

// One block per PSF point. 256 threads.
// Phase 1: load ~37 elems/thread into registers (ReLU'd), block-reduce max.
// Phase 2: atomicAdd scaled values into output with bounds clipping.
__global__ __launch_bounds__(256) void scatter_psf_kernel(
    const float* __restrict__ psf_raw,
    const float* __restrict__ i_val,
    const int*   __restrict__ bArr,
    const int*   __restrict__ chArr,
    const int*   __restrict__ zArr,
    const int*   __restrict__ yArr,
    const int*   __restrict__ xArr,
    float*       __restrict__ out)
{
    const int n   = blockIdx.x;
    const int tid = threadIdx.x;
    const float* p = psf_raw + (size_t)n * PSF3;

    // ---- Phase 1: load + ReLU + local max ----
    float v[VPT];
    float m = 0.0f;
#pragma unroll
    for (int k = 0; k < VPT; ++k) {
        int idx = tid + (k << 8);
        float val = (idx < PSF3) ? p[idx] : 0.0f;
        val = fmaxf(val, 0.0f);
        v[k] = val;
        m = fmaxf(m, val);
    }

    // wave (64-lane) max reduce
#pragma unroll
    for (int off = 32; off > 0; off >>= 1)
        m = fmaxf(m, __shfl_down(m, off, 64));

    __shared__ float smax[4];
    if ((tid & 63) == 0) smax[tid >> 6] = m;
    __syncthreads();
    const float mm = fmaxf(fmaxf(smax[0], smax[1]), fmaxf(smax[2], smax[3]));

    // scale = SCALE * relu(i_val) / max   (max > 0 with overwhelming prob., matches ref semantics)
    const float scale = SCALE_F * fmaxf(i_val[n], 0.0f) / mm;

    // ---- Phase 2: scatter ----
    const int C = 16, H = 256, W = 256, D = 64;
    const int c  = bArr[n] * C + chArr[n];
    const int z0 = zArr[n] - PAD;
    const int y0 = yArr[n] - PAD;
    const int x0 = xArr[n] - PAD;
    float* outc = out + (size_t)c * H * W * D;

#pragma unroll
    for (int k = 0; k < VPT; ++k) {
        int idx = tid + (k << 8);
        if (idx < PSF3) {
            float val = v[k];
            if (val > 0.0f) {
                int iz  = idx / 441;            // 21*21
                int rem = idx - iz * 441;
                int iy  = rem / 21;
                int ix  = rem - iy * 21;
                int zz = z0 + iz;
                int yy = y0 + iy;
                int xx = x0 + ix;
                if ((unsigned)zz < (unsigned)H &&
                    (unsigned)yy < (unsigned)W &&
                    (unsigned)xx < (unsigned)D) {
                    size_t o = (((size_t)zz * W) + yy) * D + xx;
                    atomicAdd(outc + o, val * scale);
                }
            }
        }
    }
}

extern "C" void kernel_launch(void* const* d_in, const int* in_sizes, int n_in,
                              void* d_out, int out_size, void* d_ws, size_t ws_size,
                              hipStream_t stream) {
    const float* psf_raw = (const float*)d_in[0];
    const float* i_val   = (const float*)d_in[1];
    const int*   bArr    = (const int*)d_in[2];
    const int*   chArr   = (const int*)d_in[3];
    const int*   zArr    = (const int*)d_in[4];
    const int*   yArr    = (const int*)d_in[5];
    const int*   xArr    = (const int*)d_in[6];
    float* out = (float*)d_out;

    const int N = in_sizes[1];   // 8192 points

    // zero the output (harness poisons it; atomics need zero base)
    hipMemsetAsync(d_out, 0, (size_t)out_size * sizeof(float), stream);

    scatter_psf_kernel<<<N, 256, 0, stream>>>(psf_raw, i_val, bArr, chArr,
                                              zArr, yArr, xArr, out);
}